// Round 6
// baseline (1563.204 us; speedup 1.0000x reference)
//
#include <hip/hip_runtime.h>
#include <stdint.h>

// Problem constants (B=2, L=2048, D=2048, E=8, Dg=256, k=2)
#define T_TOK 4096
#define DIM   2048
#define NEXP  8
#define DG    256
#define TOPK  2

// Tiling: up 64x128 (48KB LDS), down 64x64 (32KB), BKU=64, 4 waves/block.
#define BM 64
#define BN 128
#define BND 64
#define BKU 64
#define NROWS  (T_TOK*TOPK + NEXP*BM)   // 8704 padded row capacity
#define NBLK_M (NROWS/BM)               // 136 M-blocks
#define NT_DOWN (NBLK_M*(DG/BND))       // 544 down tiles
#define NT_UP   (NBLK_M*(DIM/BN))       // 2176 up tiles

// Persistent grid: EXACTLY 3 blocks/CU x 256 CU. Co-residency guaranteed:
// LDS 48KB -> floor(160/48)=3 blocks/CU; __launch_bounds__(256,3) caps VGPR
// for 12 waves/CU; 768 blocks therefore all resident -> spin barrier safe.
#define NBLK 768

typedef __attribute__((ext_vector_type(8))) short short8;
typedef __attribute__((ext_vector_type(4))) float f32x4;

static __device__ __forceinline__ short f2bf(float f) {
    union { float f; uint32_t u; } v{f};
    uint32_t r = v.u + 0x7fffu + ((v.u >> 16) & 1u);   // RNE
    return (short)(r >> 16);
}
static __device__ __forceinline__ float b2f(short s) {
    union { uint32_t u; float f; } v{((uint32_t)(unsigned short)s) << 16};
    return v.f;
}

#define AS3 __attribute__((address_space(3)))
#define GLD16(g, l) \
    __builtin_amdgcn_global_load_lds((const __attribute__((address_space(1))) void*)(g), \
                                     (AS3 void*)(l), 16, 0, 0)
#define VMCNT(N) asm volatile("s_waitcnt vmcnt(" #N ")" ::: "memory")
#define BAR()    __builtin_amdgcn_s_barrier()

// Generation-counting grid barrier. Device-scope atomics + __threadfence
// (L2 writeback/invalidate) for cross-XCD visibility of plain stores.
static __device__ __forceinline__ void grid_barrier(int* bar) {
    __syncthreads();
    if (threadIdx.x == 0) {
        __threadfence();                                   // release my block's writes
        int g = __hip_atomic_load(&bar[1], __ATOMIC_RELAXED, __HIP_MEMORY_SCOPE_AGENT);
        int v = __hip_atomic_fetch_add(&bar[0], 1, __ATOMIC_ACQ_REL, __HIP_MEMORY_SCOPE_AGENT);
        if (v == NBLK - 1) {
            __hip_atomic_store(&bar[0], 0, __ATOMIC_RELAXED, __HIP_MEMORY_SCOPE_AGENT);
            __hip_atomic_fetch_add(&bar[1], 1, __ATOMIC_RELEASE, __HIP_MEMORY_SCOPE_AGENT);
        } else {
            while (__hip_atomic_load(&bar[1], __ATOMIC_ACQUIRE, __HIP_MEMORY_SCOPE_AGENT) == g)
                __builtin_amdgcn_s_sleep(2);
        }
        __threadfence();                                   // acquire others' writes
    }
    __syncthreads();
}

__global__ void init_bar(int* bar) {
    if (threadIdx.x < 32) bar[threadIdx.x] = 0;
}

// ---------------------------------------------------------------------------
// GEMM macros (same verified bodies as rounds 2-5).
// ---------------------------------------------------------------------------
#define STAGE_D(B_) do { \
    GLD16(agA0, lA_##B_##_0); \
    GLD16(agA1, lA_##B_##_1); \
    GLD16(agB0, lB_##B_##_0); \
    GLD16(agB1, lB_##B_##_1); \
    agA0 += BKU; agA1 += BKU; \
    agB0 += BKU; agB1 += BKU; \
} while (0)

#define COMP_D(B_) do { \
    short8 a00 = *(const short8*)&As[B_][am0][c0]; \
    short8 a10 = *(const short8*)&As[B_][am1][c0]; \
    short8 b00 = *(const short8*)&Bs[B_][bn0][c0]; \
    short8 b10 = *(const short8*)&Bs[B_][bn1][c0]; \
    short8 a01 = *(const short8*)&As[B_][am0][c1]; \
    short8 a11 = *(const short8*)&As[B_][am1][c1]; \
    short8 b01 = *(const short8*)&Bs[B_][bn0][c1]; \
    short8 b11 = *(const short8*)&Bs[B_][bn1][c1]; \
    acc[0][0] = __builtin_amdgcn_mfma_f32_16x16x32_bf16(a00, b00, acc[0][0], 0, 0, 0); \
    acc[0][1] = __builtin_amdgcn_mfma_f32_16x16x32_bf16(a00, b10, acc[0][1], 0, 0, 0); \
    acc[1][0] = __builtin_amdgcn_mfma_f32_16x16x32_bf16(a10, b00, acc[1][0], 0, 0, 0); \
    acc[1][1] = __builtin_amdgcn_mfma_f32_16x16x32_bf16(a10, b10, acc[1][1], 0, 0, 0); \
    acc[0][0] = __builtin_amdgcn_mfma_f32_16x16x32_bf16(a01, b01, acc[0][0], 0, 0, 0); \
    acc[0][1] = __builtin_amdgcn_mfma_f32_16x16x32_bf16(a01, b11, acc[0][1], 0, 0, 0); \
    acc[1][0] = __builtin_amdgcn_mfma_f32_16x16x32_bf16(a11, b01, acc[1][0], 0, 0, 0); \
    acc[1][1] = __builtin_amdgcn_mfma_f32_16x16x32_bf16(a11, b11, acc[1][1], 0, 0, 0); \
} while (0)

#define STAGE_B(B_) do { \
    GLD16(agB0, lB_##B_##_0); \
    GLD16(agB1, lB_##B_##_1); \
    GLD16(agB2, lB_##B_##_2); \
    GLD16(agB3, lB_##B_##_3); \
    agB0 += BKU; agB1 += BKU; agB2 += BKU; agB3 += BKU; \
} while (0)

#define STAGE_A(B_, kb) do { \
    short8 v0 = *(const short8*)(dr00 + (kb)); \
    short8 v1 = *(const short8*)(dr01 + (kb)); \
    short8 u0 = *(const short8*)(dr10 + (kb)); \
    short8 u1 = *(const short8*)(dr11 + (kb)); \
    short8 o0, o1; \
    _Pragma("unroll") \
    for (int jq = 0; jq < 8; jq++) { \
        o0[jq] = f2bf(g00 * b2f(v0[jq]) + g01 * b2f(v1[jq])); \
        o1[jq] = f2bf(g10 * b2f(u0[jq]) + g11 * b2f(u1[jq])); \
    } \
    *(short8*)&As[B_][srow     ][cl] = o0; \
    *(short8*)&As[B_][srow + 32][cl] = o1; \
} while (0)

#define COMP_U(B_) do { \
    short8 a00 = *(const short8*)&As[B_][am0][c0]; \
    short8 a10 = *(const short8*)&As[B_][am1][c0]; \
    short8 b00 = *(const short8*)&Bs[B_][bn0][c0]; \
    short8 b10 = *(const short8*)&Bs[B_][bn1][c0]; \
    short8 b20 = *(const short8*)&Bs[B_][bn2][c0]; \
    short8 b30 = *(const short8*)&Bs[B_][bn3][c0]; \
    short8 a01 = *(const short8*)&As[B_][am0][c1]; \
    short8 a11 = *(const short8*)&As[B_][am1][c1]; \
    short8 b01 = *(const short8*)&Bs[B_][bn0][c1]; \
    short8 b11 = *(const short8*)&Bs[B_][bn1][c1]; \
    short8 b21 = *(const short8*)&Bs[B_][bn2][c1]; \
    short8 b31 = *(const short8*)&Bs[B_][bn3][c1]; \
    acc[0][0] = __builtin_amdgcn_mfma_f32_16x16x32_bf16(a00, b00, acc[0][0], 0, 0, 0); \
    acc[0][1] = __builtin_amdgcn_mfma_f32_16x16x32_bf16(a00, b10, acc[0][1], 0, 0, 0); \
    acc[0][2] = __builtin_amdgcn_mfma_f32_16x16x32_bf16(a00, b20, acc[0][2], 0, 0, 0); \
    acc[0][3] = __builtin_amdgcn_mfma_f32_16x16x32_bf16(a00, b30, acc[0][3], 0, 0, 0); \
    acc[1][0] = __builtin_amdgcn_mfma_f32_16x16x32_bf16(a10, b00, acc[1][0], 0, 0, 0); \
    acc[1][1] = __builtin_amdgcn_mfma_f32_16x16x32_bf16(a10, b10, acc[1][1], 0, 0, 0); \
    acc[1][2] = __builtin_amdgcn_mfma_f32_16x16x32_bf16(a10, b20, acc[1][2], 0, 0, 0); \
    acc[1][3] = __builtin_amdgcn_mfma_f32_16x16x32_bf16(a10, b30, acc[1][3], 0, 0, 0); \
    acc[0][0] = __builtin_amdgcn_mfma_f32_16x16x32_bf16(a01, b01, acc[0][0], 0, 0, 0); \
    acc[0][1] = __builtin_amdgcn_mfma_f32_16x16x32_bf16(a01, b11, acc[0][1], 0, 0, 0); \
    acc[0][2] = __builtin_amdgcn_mfma_f32_16x16x32_bf16(a01, b21, acc[0][2], 0, 0, 0); \
    acc[0][3] = __builtin_amdgcn_mfma_f32_16x16x32_bf16(a01, b31, acc[0][3], 0, 0, 0); \
    acc[1][0] = __builtin_amdgcn_mfma_f32_16x16x32_bf16(a11, b01, acc[1][0], 0, 0, 0); \
    acc[1][1] = __builtin_amdgcn_mfma_f32_16x16x32_bf16(a11, b11, acc[1][1], 0, 0, 0); \
    acc[1][2] = __builtin_amdgcn_mfma_f32_16x16x32_bf16(a11, b21, acc[1][2], 0, 0, 0); \
    acc[1][3] = __builtin_amdgcn_mfma_f32_16x16x32_bf16(a11, b31, acc[1][3], 0, 0, 0); \
} while (0)

// ---------------------------------------------------------------------------
// Persistent mega-kernel: gate+convW (partitioned) -> bucket (block 0,
// overlapped with convW tail) -> [bar] -> down GEMM -> [bar] -> up GEMM
// (fused combine1) -> [bar] -> combine2.
// ---------------------------------------------------------------------------
__global__ __launch_bounds__(256, 3) void moe_mega(
    const float* __restrict__ x,  const float* __restrict__ Wg,
    const float* __restrict__ Wd, const float* __restrict__ Wu,
    float* __restrict__ out, int* __restrict__ bar,
    int* __restrict__ gidx, float* __restrict__ gval,
    int* __restrict__ rowtok, int* __restrict__ rowpos, int* __restrict__ seg_off,
    short* __restrict__ x_bf, short* __restrict__ Wd_bf, short* __restrict__ Wu_bf,
    short* __restrict__ dr_bf, short* __restrict__ ur_bf)
{
    __shared__ __align__(16) char smem[49152];
    int bid = blockIdx.x;
    int tid = threadIdx.x;

    // ============ Phase A: gate (blocks 0..255) | convW (256..767) ============
    if (bid < 256) {
        int wid = tid >> 6, lane = tid & 63;
#pragma unroll 1
        for (int it = 0; it < 4; ++it) {
            int token = bid * 16 + it * 4 + wid;
            const float4* xr = (const float4*)(x + (size_t)token * DIM);
            float4 xv[8];
#pragma unroll
            for (int i = 0; i < 8; i++) xv[i] = xr[lane + 64 * i];
            short4* xb = (short4*)(x_bf + (size_t)token * DIM);
#pragma unroll
            for (int i = 0; i < 8; i++) {
                short4 o;
                o.x = f2bf(xv[i].x); o.y = f2bf(xv[i].y);
                o.z = f2bf(xv[i].z); o.w = f2bf(xv[i].w);
                xb[lane + 64 * i] = o;
            }
            float acc[NEXP];
#pragma unroll
            for (int e = 0; e < NEXP; e++) {
                const float4* wr = (const float4*)(Wg + e * DIM);
                float a = 0.0f;
#pragma unroll
                for (int i = 0; i < 8; i++) {
                    float4 w = wr[lane + 64 * i];
                    a += xv[i].x * w.x + xv[i].y * w.y + xv[i].z * w.z + xv[i].w * w.w;
                }
                acc[e] = a;
            }
#pragma unroll
            for (int m = 1; m < 64; m <<= 1) {
#pragma unroll
                for (int e = 0; e < NEXP; e++) acc[e] += __shfl_xor(acc[e], m, 64);
            }
            if (lane == 0) {
                float sg[NEXP];
#pragma unroll
                for (int e = 0; e < NEXP; e++) sg[e] = 1.0f / (1.0f + expf(-acc[e]));
                int i0 = 0;
#pragma unroll
                for (int e = 1; e < NEXP; e++) if (sg[e] > sg[i0]) i0 = e;  // strict >
                int i1 = (i0 == 0) ? 1 : 0;
#pragma unroll
                for (int e = 0; e < NEXP; e++) if (e != i0 && e != i1 && sg[e] > sg[i1]) i1 = e;
                gidx[2 * token + 0] = i0;
                gidx[2 * token + 1] = i1;
                gval[2 * token + 0] = sg[i0];
                gval[2 * token + 1] = sg[i1];
            }
        }
        // gate-group arrival (sub-barrier so bucket can start under convW)
        __syncthreads();
        if (tid == 0) {
            __threadfence();
            __hip_atomic_fetch_add(&bar[2], 1, __ATOMIC_ACQ_REL, __HIP_MEMORY_SCOPE_AGENT);
        }
        if (bid == 0) {
            if (tid == 0) {
                while (__hip_atomic_load(&bar[2], __ATOMIC_ACQUIRE, __HIP_MEMORY_SCOPE_AGENT) < 256)
                    __builtin_amdgcn_s_sleep(2);
                __threadfence();
            }
            __syncthreads();
            // ---- bucket (256 threads, ballot counting + mask-prefix scatter) ----
            int* cnt = (int*)smem;
            int* cur = cnt + NEXP;
            int lane_ = tid & 63;
            if (tid < NEXP) cnt[tid] = 0;
            __syncthreads();
            int e_[32];
#pragma unroll
            for (int r = 0; r < 32; r++) e_[r] = gidx[r * 256 + tid];
            int mycnt = 0;
#pragma unroll
            for (int r = 0; r < 32; r++) {
                int e = e_[r];
#pragma unroll
                for (int ee = 0; ee < NEXP; ee++) {
                    unsigned long long m = __ballot(e == ee);
                    if (lane_ == ee) mycnt += (int)__popcll(m);
                }
            }
            if (lane_ < NEXP) atomicAdd(&cnt[lane_], mycnt);
            __syncthreads();
            if (tid == 0) {
                int o = 0;
                for (int e = 0; e < NEXP; e++) {
                    seg_off[e] = o; cur[e] = o;
                    o += ((cnt[e] + BM - 1) / BM) * BM;
                }
                seg_off[NEXP] = o;
            }
            __syncthreads();
            for (int r = tid; r < NROWS; r += 256) rowtok[r] = -1;
            __syncthreads();
#pragma unroll 1
            for (int r = 0; r < 32; r++) {
                int idx = r * 256 + tid;
                int e = e_[r];
#pragma unroll
                for (int ee = 0; ee < NEXP; ee++) {
                    unsigned long long m = __ballot(e == ee);
                    if (m == 0) continue;                    // wave-uniform
                    int leader = __ffsll((unsigned long long)m) - 1;
                    int base = 0;
                    if (lane_ == leader) base = atomicAdd(&cur[ee], (int)__popcll(m));
                    base = __shfl(base, leader, 64);
                    if (e == ee) {
                        int pos = base + (int)__popcll(m & ((1ull << lane_) - 1ull));
                        rowtok[pos] = idx >> 1;
                        rowpos[idx] = pos;
                    }
                }
            }
        }
    } else {
        // ---- convW: 512 blocks x 16 jobs x 256 float4 = both weight tensors ----
        const int n4 = NEXP * DG * DIM / 4;               // 1048576 per tensor
#pragma unroll 1
        for (int it = 0; it < 16; ++it) {
            int i = (bid - 256) * 4096 + it * 256 + tid;  // < 2*n4 exactly
            const float* s; short* dptr; int j;
            if (i < n4) { s = Wd; dptr = Wd_bf; j = i; }
            else        { s = Wu; dptr = Wu_bf; j = i - n4; }
            float4 v = ((const float4*)s)[j];
            short4 o;
            o.x = f2bf(v.x); o.y = f2bf(v.y); o.z = f2bf(v.z); o.w = f2bf(v.w);
            ((short4*)dptr)[j] = o;
        }
    }
    grid_barrier(bar);

    // ============ Phase B: down GEMM (544 tiles, counted-vmcnt dbuf) ============
    if (bid < NT_DOWN) {
        int lid = (bid & 7) * 68 + (bid >> 3);    // XCD chunking
        int bx = lid >> 2, by = lid & 3;
        int row0 = bx * BM;
        int total = seg_off[NEXP];
        if (row0 < total) {
            short (*As)[BM][BKU]  = (short (*)[BM][BKU])smem;           // 16 KB
            short (*Bs)[BND][BKU] = (short (*)[BND][BKU])(smem + 16384); // 16 KB
            int e = 0;
            while (row0 >= seg_off[e + 1]) ++e;
            int n0 = by * BND;
            int w = tid >> 6, l = tid & 63;
            int srow = (w << 3) + (l >> 3);
            int sc   = ((l & 7) ^ ((l >> 3) & 7)) << 3;
            int ta0 = rowtok[row0 + srow];      if (ta0 < 0) ta0 = 0;
            int ta1 = rowtok[row0 + 32 + srow]; if (ta1 < 0) ta1 = 0;
            const short* agA0 = x_bf + (size_t)ta0 * DIM + sc;
            const short* agA1 = x_bf + (size_t)ta1 * DIM + sc;
            const short* be = Wd_bf + (size_t)e * DG * DIM + (size_t)n0 * DIM;
            const short* agB0 = be + (size_t)(srow     ) * DIM + sc;
            const short* agB1 = be + (size_t)(srow + 32) * DIM + sc;
            auto lA_0_0 = (AS3 void*)&As[0][(w << 3)     ][0];
            auto lA_0_1 = (AS3 void*)&As[0][(w << 3) + 32][0];
            auto lA_1_0 = (AS3 void*)&As[1][(w << 3)     ][0];
            auto lA_1_1 = (AS3 void*)&As[1][(w << 3) + 32][0];
            auto lB_0_0 = (AS3 void*)&Bs[0][(w << 3)     ][0];
            auto lB_0_1 = (AS3 void*)&Bs[0][(w << 3) + 32][0];
            auto lB_1_0 = (AS3 void*)&Bs[1][(w << 3)     ][0];
            auto lB_1_1 = (AS3 void*)&Bs[1][(w << 3) + 32][0];
            int mlane = l & 15, qlane = l >> 4;
            int wm = w >> 1, wn = w & 1;
            int c0 = (qlane ^ (mlane & 7)) << 3;
            int c1 = c0 ^ 32;
            int am0 = wm * 32 + mlane, am1 = am0 + 16;
            int bn0 = wn * 32 + mlane, bn1 = bn0 + 16;
            f32x4 acc[2][2] = {};
            constexpr int NT = DIM / BKU;          // 32
            STAGE_D(0);
            STAGE_D(1);
#pragma unroll 1
            for (int t = 0; t < NT - 2; t += 2) {
                VMCNT(4); BAR();
                COMP_D(0);
                BAR();
                STAGE_D(0);
                VMCNT(4); BAR();
                COMP_D(1);
                BAR();
                if (t + 3 < NT) STAGE_D(1);
            }
            VMCNT(4); BAR();
            COMP_D(0);
            BAR();
            VMCNT(0); BAR();
            COMP_D(1);
#pragma unroll
            for (int i = 0; i < 2; i++) {
                int rbase = row0 + wm * 32 + i * 16 + qlane * 4;
#pragma unroll
                for (int j = 0; j < 2; j++) {
                    int col = n0 + wn * 32 + j * 16 + mlane;
#pragma unroll
                    for (int r = 0; r < 4; r++)
                        dr_bf[(size_t)(rbase + r) * DG + col] = f2bf(acc[i][j][r]);
                }
            }
        }
    }
    grid_barrier(bar);

    // ============ Phase C: up GEMM (2176 tiles, fused combine1) ============
#pragma unroll 1
    for (int jj = bid; jj < NT_UP; jj += NBLK) {
        __syncthreads();                           // LDS handoff between tiles
        int lid = (jj & 7) * 272 + (jj >> 3);      // XCD chunking
        int bx = lid % NBLK_M, by = lid / NBLK_M;
        int row0 = bx * BM;
        int total = seg_off[NEXP];
        if (row0 < total) {
            short (*As)[BM][BKU] = (short (*)[BM][BKU])smem;            // 16 KB
            short (*Bs)[BN][BKU] = (short (*)[BN][BKU])(smem + 16384);  // 32 KB
            int e = 0;
            while (row0 >= seg_off[e + 1]) ++e;
            int n0 = by * BN;
            int w = tid >> 6, l = tid & 63;
            int srow = (w << 3) + (l >> 3);
            int sc   = ((l & 7) ^ ((l >> 3) & 7)) << 3;
            int cl   = (l & 7) << 3;
            int t0 = rowtok[row0 + srow];      if (t0 < 0) t0 = 0;
            int t1 = rowtok[row0 + 32 + srow]; if (t1 < 0) t1 = 0;
            int   p00 = rowpos[2 * t0], p01 = rowpos[2 * t0 + 1];
            int   p10 = rowpos[2 * t1], p11 = rowpos[2 * t1 + 1];
            float g00 = gval[2 * t0],   g01 = gval[2 * t0 + 1];
            float g10 = gval[2 * t1],   g11 = gval[2 * t1 + 1];
            const short* dr00 = dr_bf + (size_t)p00 * DG + sc;
            const short* dr01 = dr_bf + (size_t)p01 * DG + sc;
            const short* dr10 = dr_bf + (size_t)p10 * DG + sc;
            const short* dr11 = dr_bf + (size_t)p11 * DG + sc;
            const short* be = Wu_bf + (size_t)e * DIM * DG + (size_t)n0 * DG;
            const short* agB0 = be + (size_t)(srow     ) * DG + sc;
            const short* agB1 = be + (size_t)(srow + 32) * DG + sc;
            const short* agB2 = be + (size_t)(srow + 64) * DG + sc;
            const short* agB3 = be + (size_t)(srow + 96) * DG + sc;
            auto lB_0_0 = (AS3 void*)&Bs[0][(w << 3)     ][0];
            auto lB_0_1 = (AS3 void*)&Bs[0][(w << 3) + 32][0];
            auto lB_0_2 = (AS3 void*)&Bs[0][(w << 3) + 64][0];
            auto lB_0_3 = (AS3 void*)&Bs[0][(w << 3) + 96][0];
            auto lB_1_0 = (AS3 void*)&Bs[1][(w << 3)     ][0];
            auto lB_1_1 = (AS3 void*)&Bs[1][(w << 3) + 32][0];
            auto lB_1_2 = (AS3 void*)&Bs[1][(w << 3) + 64][0];
            auto lB_1_3 = (AS3 void*)&Bs[1][(w << 3) + 96][0];
            int mlane = l & 15, qlane = l >> 4;
            int wm = w >> 1, wn = w & 1;
            int c0 = (qlane ^ (mlane & 7)) << 3;
            int c1 = c0 ^ 32;
            int am0 = wm * 32 + mlane, am1 = am0 + 16;
            int bn0 = wn * 64 + mlane, bn1 = bn0 + 16, bn2 = bn0 + 32, bn3 = bn0 + 48;
            f32x4 acc[2][4] = {};
            STAGE_A(0, 0); STAGE_B(0);
            __syncthreads();
            STAGE_A(1, BKU); STAGE_B(1);
            COMP_U(0);
            __syncthreads();
            STAGE_A(0, 2 * BKU); STAGE_B(0);
            COMP_U(1);
            __syncthreads();
            STAGE_A(1, 3 * BKU); STAGE_B(1);
            COMP_U(0);
            __syncthreads();
            COMP_U(1);
#pragma unroll
            for (int i = 0; i < 2; i++) {
                int rbase = row0 + wm * 32 + i * 16 + qlane * 4;
#pragma unroll
                for (int j = 0; j < 4; j++) {
                    int col = n0 + wn * 64 + j * 16 + mlane;
#pragma unroll
                    for (int r = 0; r < 4; r++)
                        ur_bf[(size_t)(rbase + r) * DIM + col] = f2bf(acc[i][j][r]);
                }
            }
        }
    }
    grid_barrier(bar);

    // ============ Phase D: combine2 ============
    int gid = bid * 256 + tid;
#pragma unroll 1
    for (int i = gid; i < T_TOK * DIM / 4; i += NBLK * 256) {
        int t = i >> 9;                           // D/4 = 512
        int c = (i & 511) * 4;
        int   p0 = rowpos[2 * t], p1 = rowpos[2 * t + 1];
        float g0 = gval[2 * t],   g1 = gval[2 * t + 1];
        short4 u0 = *(const short4*)&ur_bf[(size_t)p0 * DIM + c];
        short4 u1 = *(const short4*)&ur_bf[(size_t)p1 * DIM + c];
        float4 o;
        o.x = g0 * b2f(u0.x) + g1 * b2f(u1.x);
        o.y = g0 * b2f(u0.y) + g1 * b2f(u1.y);
        o.z = g0 * b2f(u0.z) + g1 * b2f(u1.z);
        o.w = g0 * b2f(u0.w) + g1 * b2f(u1.w);
        *(float4*)&out[(size_t)t * DIM + c] = o;
    }
}

extern "C" void kernel_launch(void* const* d_in, const int* in_sizes, int n_in,
                              void* d_out, int out_size, void* d_ws, size_t ws_size,
                              hipStream_t stream) {
    const float* x  = (const float*)d_in[0];
    const float* Wg = (const float*)d_in[1];
    const float* Wd = (const float*)d_in[2];
    const float* Wu = (const float*)d_in[3];
    float* out = (float*)d_out;

    char* p = (char*)d_ws;
    int*   bar     = (int*)(p + 0);                       // 128 (zeroed by init_bar)
    int*   gidx    = (int*)(p + 128);                     // 32768
    float* gval    = (float*)(p + 32896);                 // 32768
    int*   rowtok  = (int*)(p + 65664);                   // 34816
    int*   rowpos  = (int*)(p + 100480);                  // 32768
    int*   seg_off = (int*)(p + 133248);                  // 384 (padded)
    short* x_bf    = (short*)(p + 133632);                // 16777216
    short* Wd_bf   = (short*)(p + 133632 + 16777216);     // 8388608
    short* Wu_bf   = Wd_bf + 4194304;                     // 8388608
    short* dr_bf   = Wu_bf + 4194304;                     // NROWS*DG*2  = 4456448
    short* ur_bf   = dr_bf + (size_t)NROWS * DG;          // NROWS*DIM*2 = 35651584

    init_bar<<<1, 64, 0, stream>>>(bar);
    moe_mega<<<NBLK, 256, 0, stream>>>(x, Wg, Wd, Wu, out, bar,
                                       gidx, gval, rowtok, rowpos, seg_off,
                                       x_bf, Wd_bf, Wu_bf, dr_bf, ur_bf);
}

// Round 7
// 196.965 us; speedup vs baseline: 7.9365x; 7.9365x over previous
//
#include <hip/hip_runtime.h>
#include <stdint.h>

// Problem constants (B=2, L=2048, D=2048, E=8, Dg=256, k=2)
#define T_TOK 4096
#define DIM   2048
#define NEXP  8
#define DG    256
#define TOPK  2

// GEMM tiling: block tile 64(M) x 128(N), BKU=64, 4 waves of 32x64 each,
// double-buffered LDS with 1-deep prefetch (T3-minimal 2-phase).
#define BM 64
#define BN 128
#define BKU 64
#define NROWS  (T_TOK*TOPK + NEXP*BM)   // 8704 padded row capacity
#define NBLK_M (NROWS/BM)               // 136 M-blocks

typedef __attribute__((ext_vector_type(8))) short short8;
typedef __attribute__((ext_vector_type(4))) float f32x4;

static __device__ __forceinline__ short f2bf(float f) {
    union { float f; uint32_t u; } v{f};
    uint32_t r = v.u + 0x7fffu + ((v.u >> 16) & 1u);   // RNE
    return (short)(r >> 16);
}
static __device__ __forceinline__ float b2f(short s) {
    union { uint32_t u; float f; } v{((uint32_t)(unsigned short)s) << 16};
    return v.f;
}

#define GLD16(g, l) \
    __builtin_amdgcn_global_load_lds((const __attribute__((address_space(1))) void*)(g), \
                                     (__attribute__((address_space(3))) void*)(l), 16, 0, 0)

// ---------------------------------------------------------------------------
// Gate + x->bf16 fusion. One wave per token.
// ---------------------------------------------------------------------------
__global__ __launch_bounds__(256) void gate_kernel(const float* __restrict__ x,
                                                   const float* __restrict__ Wg,
                                                   int* __restrict__ gidx,
                                                   float* __restrict__ gval,
                                                   short* __restrict__ x_bf)
{
    int token = blockIdx.x * 4 + (threadIdx.x >> 6);
    int lane  = threadIdx.x & 63;
    const float4* xr = (const float4*)(x + (size_t)token * DIM);

    float4 xv[8];
#pragma unroll
    for (int i = 0; i < 8; i++) xv[i] = xr[lane + 64 * i];

    short4* xb = (short4*)(x_bf + (size_t)token * DIM);
#pragma unroll
    for (int i = 0; i < 8; i++) {
        short4 o;
        o.x = f2bf(xv[i].x); o.y = f2bf(xv[i].y);
        o.z = f2bf(xv[i].z); o.w = f2bf(xv[i].w);
        xb[lane + 64 * i] = o;
    }

    float acc[NEXP];
#pragma unroll
    for (int e = 0; e < NEXP; e++) {
        const float4* wr = (const float4*)(Wg + e * DIM);
        float a = 0.0f;
#pragma unroll
        for (int i = 0; i < 8; i++) {
            float4 w = wr[lane + 64 * i];
            a += xv[i].x * w.x + xv[i].y * w.y + xv[i].z * w.z + xv[i].w * w.w;
        }
        acc[e] = a;
    }

#pragma unroll
    for (int m = 1; m < 64; m <<= 1) {
#pragma unroll
        for (int e = 0; e < NEXP; e++) acc[e] += __shfl_xor(acc[e], m, 64);
    }

    if (lane == 0) {
        float sg[NEXP];
#pragma unroll
        for (int e = 0; e < NEXP; e++) sg[e] = 1.0f / (1.0f + expf(-acc[e]));
        int i0 = 0;
#pragma unroll
        for (int e = 1; e < NEXP; e++) if (sg[e] > sg[i0]) i0 = e;   // strict >: lowest index wins
        int i1 = (i0 == 0) ? 1 : 0;
#pragma unroll
        for (int e = 0; e < NEXP; e++) if (e != i0 && e != i1 && sg[e] > sg[i1]) i1 = e;
        gidx[2 * token + 0] = i0;
        gidx[2 * token + 1] = i1;
        gval[2 * token + 0] = sg[i0];
        gval[2 * token + 1] = sg[i1];
    }
}

// ---------------------------------------------------------------------------
// Weight fp32 -> bf16 (Wd and Wu in one launch).
// ---------------------------------------------------------------------------
__global__ __launch_bounds__(256) void convW_kernel(const float* __restrict__ Wd,
                                                    const float* __restrict__ Wu,
                                                    short* __restrict__ Wd_bf,
                                                    short* __restrict__ Wu_bf,
                                                    int n4)
{
    int i = blockIdx.x * 256 + threadIdx.x;
    const float* s; short* d; int j;
    if (i < n4)      { s = Wd; d = Wd_bf; j = i; }
    else             { s = Wu; d = Wu_bf; j = i - n4; if (j >= n4) return; }
    float4 v = ((const float4*)s)[j];
    short4 o;
    o.x = f2bf(v.x); o.y = f2bf(v.y); o.z = f2bf(v.z); o.w = f2bf(v.w);
    ((short4*)d)[j] = o;
}

// ---------------------------------------------------------------------------
// Bucket rows by expert (segments padded to BM).
// ---------------------------------------------------------------------------
__global__ __launch_bounds__(1024) void bucket_kernel(const int* __restrict__ gidx,
                                                      int* __restrict__ rowtok,
                                                      int* __restrict__ rowpos,
                                                      int* __restrict__ seg_off)
{
    __shared__ int cnt[NEXP];
    __shared__ int cur[NEXP];
    int tid = threadIdx.x;
    if (tid < NEXP) cnt[tid] = 0;
    __syncthreads();

    for (int t = tid; t < T_TOK; t += 1024) {
        atomicAdd(&cnt[gidx[2 * t + 0]], 1);
        atomicAdd(&cnt[gidx[2 * t + 1]], 1);
    }
    __syncthreads();

    if (tid == 0) {
        int o = 0;
        for (int e = 0; e < NEXP; e++) {
            seg_off[e] = o;
            cur[e] = o;
            o += ((cnt[e] + BM - 1) / BM) * BM;
        }
        seg_off[NEXP] = o;
    }
    __syncthreads();

    for (int r = tid; r < NROWS; r += 1024) rowtok[r] = -1;
    __syncthreads();

    for (int t = tid; t < T_TOK; t += 1024) {
        for (int s = 0; s < TOPK; s++) {
            int e = gidx[2 * t + s];
            int p = atomicAdd(&cur[e], 1);
            rowtok[p] = t;
            rowpos[2 * t + s] = p;
        }
    }
}

// ---------------------------------------------------------------------------
// Grouped GEMM (bf16 MFMA), double-buffered 2-phase pipeline:
//   prologue STAGE(buf0); per 64-wide K-tile: STAGE(next buf) issued BEFORE
//   compute of current buf; single __syncthreads() per tile. With ~3 blocks/CU
//   of TLP the barrier drain overlaps across waves (m114 mechanism).
// LDS rows are 128 B (alias all 32 banks) -> chunk-XOR swizzle (chunk ^= row&7)
// applied on the GLOBAL source (linear LDS dest, per global_load_lds rules);
// fragment ds_read_b128 then lands 8 lanes on each 16 B chunk = balanced.
// ---------------------------------------------------------------------------
#define AS3 __attribute__((address_space(3)))

#define STAGE(B_) do { \
    GLD16(agA0, lA_##B_##_0); \
    GLD16(agA1, lA_##B_##_1); \
    GLD16(agB0, lB_##B_##_0); \
    GLD16(agB1, lB_##B_##_1); \
    GLD16(agB2, lB_##B_##_2); \
    GLD16(agB3, lB_##B_##_3); \
    agA0 += BKU; agA1 += BKU; \
    agB0 += BKU; agB1 += BKU; agB2 += BKU; agB3 += BKU; \
} while (0)

#define COMP(B_) do { \
    short8 a00 = *(const short8*)&As[B_][am0][c0]; \
    short8 a10 = *(const short8*)&As[B_][am1][c0]; \
    short8 b00 = *(const short8*)&Bs[B_][bn0][c0]; \
    short8 b10 = *(const short8*)&Bs[B_][bn1][c0]; \
    short8 b20 = *(const short8*)&Bs[B_][bn2][c0]; \
    short8 b30 = *(const short8*)&Bs[B_][bn3][c0]; \
    short8 a01 = *(const short8*)&As[B_][am0][c1]; \
    short8 a11 = *(const short8*)&As[B_][am1][c1]; \
    short8 b01 = *(const short8*)&Bs[B_][bn0][c1]; \
    short8 b11 = *(const short8*)&Bs[B_][bn1][c1]; \
    short8 b21 = *(const short8*)&Bs[B_][bn2][c1]; \
    short8 b31 = *(const short8*)&Bs[B_][bn3][c1]; \
    acc[0][0] = __builtin_amdgcn_mfma_f32_16x16x32_bf16(a00, b00, acc[0][0], 0, 0, 0); \
    acc[0][1] = __builtin_amdgcn_mfma_f32_16x16x32_bf16(a00, b10, acc[0][1], 0, 0, 0); \
    acc[0][2] = __builtin_amdgcn_mfma_f32_16x16x32_bf16(a00, b20, acc[0][2], 0, 0, 0); \
    acc[0][3] = __builtin_amdgcn_mfma_f32_16x16x32_bf16(a00, b30, acc[0][3], 0, 0, 0); \
    acc[1][0] = __builtin_amdgcn_mfma_f32_16x16x32_bf16(a10, b00, acc[1][0], 0, 0, 0); \
    acc[1][1] = __builtin_amdgcn_mfma_f32_16x16x32_bf16(a10, b10, acc[1][1], 0, 0, 0); \
    acc[1][2] = __builtin_amdgcn_mfma_f32_16x16x32_bf16(a10, b20, acc[1][2], 0, 0, 0); \
    acc[1][3] = __builtin_amdgcn_mfma_f32_16x16x32_bf16(a10, b30, acc[1][3], 0, 0, 0); \
    acc[0][0] = __builtin_amdgcn_mfma_f32_16x16x32_bf16(a01, b01, acc[0][0], 0, 0, 0); \
    acc[0][1] = __builtin_amdgcn_mfma_f32_16x16x32_bf16(a01, b11, acc[0][1], 0, 0, 0); \
    acc[0][2] = __builtin_amdgcn_mfma_f32_16x16x32_bf16(a01, b21, acc[0][2], 0, 0, 0); \
    acc[0][3] = __builtin_amdgcn_mfma_f32_16x16x32_bf16(a01, b31, acc[0][3], 0, 0, 0); \
    acc[1][0] = __builtin_amdgcn_mfma_f32_16x16x32_bf16(a11, b01, acc[1][0], 0, 0, 0); \
    acc[1][1] = __builtin_amdgcn_mfma_f32_16x16x32_bf16(a11, b11, acc[1][1], 0, 0, 0); \
    acc[1][2] = __builtin_amdgcn_mfma_f32_16x16x32_bf16(a11, b21, acc[1][2], 0, 0, 0); \
    acc[1][3] = __builtin_amdgcn_mfma_f32_16x16x32_bf16(a11, b31, acc[1][3], 0, 0, 0); \
} while (0)

template<int K, int Ntot>
__global__ __launch_bounds__(256) void gemm_kernel(const short* __restrict__ A,
                                                   const short* __restrict__ B,
                                                   const int* __restrict__ rowtok,
                                                   const int* __restrict__ seg_off,
                                                   short* __restrict__ C)
{
    __shared__ __align__(16) short As[2][BM][BKU];   // 16 KB
    __shared__ __align__(16) short Bs[2][BN][BKU];   // 32 KB

    int row0 = blockIdx.x * BM;
    int total = seg_off[NEXP];
    if (row0 >= total) return;
    int e = 0;
    while (row0 >= seg_off[e + 1]) ++e;   // BM-padded segments: block in one expert
    int n0 = blockIdx.y * BN;

    int tid = threadIdx.x;
    int w = tid >> 6, l = tid & 63;

    // ---- staging addresses: wave w covers 8 rows per 32-row round ----
    int srow = (w << 3) + (l >> 3);                 // 0..31
    int sc   = ((l & 7) ^ ((l >> 3) & 7)) << 3;     // swizzled source chunk (shorts)

    int ta0 = rowtok[row0 + srow];      if (ta0 < 0) ta0 = 0;
    int ta1 = rowtok[row0 + 32 + srow]; if (ta1 < 0) ta1 = 0;
    const short* agA0 = A + (size_t)ta0 * K + sc;
    const short* agA1 = A + (size_t)ta1 * K + sc;
    const short* be = B + (size_t)e * Ntot * K + (size_t)n0 * K;
    const short* agB0 = be + (size_t)(srow     ) * K + sc;
    const short* agB1 = be + (size_t)(srow + 32) * K + sc;
    const short* agB2 = be + (size_t)(srow + 64) * K + sc;
    const short* agB3 = be + (size_t)(srow + 96) * K + sc;

    auto lA_0_0 = (AS3 void*)&As[0][(w << 3)     ][0];
    auto lA_0_1 = (AS3 void*)&As[0][(w << 3) + 32][0];
    auto lA_1_0 = (AS3 void*)&As[1][(w << 3)     ][0];
    auto lA_1_1 = (AS3 void*)&As[1][(w << 3) + 32][0];
    auto lB_0_0 = (AS3 void*)&Bs[0][(w << 3)     ][0];
    auto lB_0_1 = (AS3 void*)&Bs[0][(w << 3) + 32][0];
    auto lB_0_2 = (AS3 void*)&Bs[0][(w << 3) + 64][0];
    auto lB_0_3 = (AS3 void*)&Bs[0][(w << 3) + 96][0];
    auto lB_1_0 = (AS3 void*)&Bs[1][(w << 3)     ][0];
    auto lB_1_1 = (AS3 void*)&Bs[1][(w << 3) + 32][0];
    auto lB_1_2 = (AS3 void*)&Bs[1][(w << 3) + 64][0];
    auto lB_1_3 = (AS3 void*)&Bs[1][(w << 3) + 96][0];

    // ---- fragment read addresses ----
    int mlane = l & 15, qlane = l >> 4;
    int wm = w >> 1, wn = w & 1;
    int c0 = (qlane ^ (mlane & 7)) << 3;   // k-chunk 0..3 (shorts, swizzled)
    int c1 = c0 ^ 32;                      // k-chunk 4..7
    int am0 = wm * 32 + mlane, am1 = am0 + 16;
    int bn0 = wn * 64 + mlane, bn1 = bn0 + 16, bn2 = bn0 + 32, bn3 = bn0 + 48;

    f32x4 acc[2][4] = {};

    STAGE(0);
    __syncthreads();
    constexpr int NT = K / BKU;            // 32 (down) or 4 (up)
#pragma unroll 1
    for (int t = 0; t < NT; t += 2) {
        if (t + 1 < NT) STAGE(1);
        COMP(0);
        __syncthreads();
        if (t + 2 < NT) STAGE(0);
        COMP(1);
        __syncthreads();
    }

    // epilogue: D layout col = lane&15, row = (lane>>4)*4 + reg  [m89-verified]
#pragma unroll
    for (int i = 0; i < 2; i++) {
        int rbase = row0 + wm * 32 + i * 16 + qlane * 4;
#pragma unroll
        for (int j = 0; j < 4; j++) {
            int col = n0 + wn * 64 + j * 16 + mlane;
#pragma unroll
            for (int r = 0; r < 4; r++)
                C[(size_t)(rbase + r) * Ntot + col] = f2bf(acc[i][j][r]);
        }
    }
}

#undef STAGE
#undef COMP
#undef AS3

// ---------------------------------------------------------------------------
// Combine down rows -> per-token down (fp32 gates), emit bf16 for up GEMM.
// ---------------------------------------------------------------------------
__global__ __launch_bounds__(256) void combine1_kernel(const short* __restrict__ dr,
                                                       const int* __restrict__ rowpos,
                                                       const float* __restrict__ gval,
                                                       short* __restrict__ dt)
{
    int t = blockIdx.x, d = threadIdx.x;
    int   p0 = rowpos[2 * t], p1 = rowpos[2 * t + 1];
    float g0 = gval[2 * t],   g1 = gval[2 * t + 1];
    float v = g0 * b2f(dr[(size_t)p0 * DG + d]) + g1 * b2f(dr[(size_t)p1 * DG + d]);
    dt[(size_t)t * DG + d] = f2bf(v);
}

// ---------------------------------------------------------------------------
// Combine up rows -> final output (fp32). short4-vectorized.
// ---------------------------------------------------------------------------
__global__ __launch_bounds__(256) void combine2_kernel(const short* __restrict__ ur,
                                                       const int* __restrict__ rowpos,
                                                       const float* __restrict__ gval,
                                                       float* __restrict__ out)
{
    int i = blockIdx.x * 256 + threadIdx.x;       // i < T*D/4
    int t = i >> 9;                               // D/4 = 512
    int c = (i & 511) * 4;
    int   p0 = rowpos[2 * t], p1 = rowpos[2 * t + 1];
    float g0 = gval[2 * t],   g1 = gval[2 * t + 1];
    short4 u0 = *(const short4*)&ur[(size_t)p0 * DIM + c];
    short4 u1 = *(const short4*)&ur[(size_t)p1 * DIM + c];
    float4 o;
    o.x = g0 * b2f(u0.x) + g1 * b2f(u1.x);
    o.y = g0 * b2f(u0.y) + g1 * b2f(u1.y);
    o.z = g0 * b2f(u0.z) + g1 * b2f(u1.z);
    o.w = g0 * b2f(u0.w) + g1 * b2f(u1.w);
    *(float4*)&out[(size_t)t * DIM + c] = o;
}

extern "C" void kernel_launch(void* const* d_in, const int* in_sizes, int n_in,
                              void* d_out, int out_size, void* d_ws, size_t ws_size,
                              hipStream_t stream) {
    const float* x  = (const float*)d_in[0];
    const float* Wg = (const float*)d_in[1];
    const float* Wd = (const float*)d_in[2];
    const float* Wu = (const float*)d_in[3];
    float* out = (float*)d_out;

    char* p = (char*)d_ws;
    int*   gidx    = (int*)(p + 0);                       // 32768
    float* gval    = (float*)(p + 32768);                 // 32768
    int*   rowtok  = (int*)(p + 65536);                   // 34816
    int*   rowpos  = (int*)(p + 100352);                  // 32768
    int*   seg_off = (int*)(p + 133120);                  // 256 (padded)
    short* x_bf    = (short*)(p + 133376);                // 16777216
    short* Wd_bf   = (short*)(p + 133376 + 16777216);     // 8388608
    short* Wu_bf   = Wd_bf + 4194304;                     // 8388608
    short* dr_bf   = Wu_bf + 4194304;                     // NROWS*DG*2  = 4456448
    short* dt_bf   = dr_bf + (size_t)NROWS * DG;          // T*DG*2      = 2097152
    short* ur_bf   = dt_bf + (size_t)T_TOK * DG;          // NROWS*DIM*2 = 35651584

    const int W4 = NEXP * DG * DIM / 4;   // 1048576 float4 per weight tensor
    gate_kernel<<<T_TOK / 4, 256, 0, stream>>>(x, Wg, gidx, gval, x_bf);
    convW_kernel<<<(2 * W4 + 255) / 256, 256, 0, stream>>>(Wd, Wu, Wd_bf, Wu_bf, W4);
    bucket_kernel<<<1, 1024, 0, stream>>>(gidx, rowtok, rowpos, seg_off);

    gemm_kernel<DIM, DG><<<dim3(NBLK_M, DG / BN), 256, 0, stream>>>(x_bf, Wd_bf, rowtok, seg_off, dr_bf);
    combine1_kernel<<<T_TOK, 256, 0, stream>>>(dr_bf, rowpos, gval, dt_bf);
    gemm_kernel<DG, DIM><<<dim3(NBLK_M, DIM / BN), 256, 0, stream>>>(dt_bf, Wu_bf, rowtok, seg_off, ur_bf);
    combine2_kernel<<<T_TOK * DIM / 4 / 256, 256, 0, stream>>>(ur_bf, rowpos, gval, out);
}